// Round 2
// baseline (750.991 us; speedup 1.0000x reference)
//
#include <hip/hip_runtime.h>
#include <hip/hip_bf16.h>
#include <math.h>

typedef __attribute__((ext_vector_type(8))) short short8;
typedef __attribute__((ext_vector_type(4))) float f32x4;
typedef __attribute__((ext_vector_type(4))) unsigned short us4;
typedef unsigned short u16;

#define TM 49
#define NV 10000

__device__ __forceinline__ u16 f2bf(float f) {
    union { float f; unsigned u; } v; v.f = f;
    unsigned r = v.u + 0x7fffu + ((v.u >> 16) & 1u);
    return (u16)(r >> 16);
}
__device__ __forceinline__ float bf2f(u16 b) {
    union { unsigned u; float f; } v; v.u = ((unsigned)b) << 16;
    return v.f;
}
__device__ __forceinline__ float sigm(float x) { return 1.0f / (1.0f + expf(-x)); }

// ---------------- sort + metadata + small outputs ----------------
__global__ __launch_bounds__(128) void k_sort(
    const int* __restrict__ caplens, const int* __restrict__ captions,
    const float* __restrict__ bih, const float* __restrict__ bhh,
    int* __restrict__ sidx, int* __restrict__ decl, int* __restrict__ capsS,
    float* __restrict__ bsum, float* __restrict__ out_tail)
{
    __shared__ int s_cl[128];
    __shared__ int s_si[128];
    int tid = threadIdx.x;
    int my = caplens[tid];
    s_cl[tid] = my;
    __syncthreads();
    int r = 0;
    for (int j = 0; j < 128; j++) {
        int cj = s_cl[j];
        if (cj > my || (cj == my && j < tid)) r++;
    }
    s_si[r] = tid;   // stable descending argsort
    __syncthreads();
    int src = s_si[tid];
    sidx[tid] = src;
    int dl = s_cl[src] - 1;
    decl[tid] = dl;
    out_tail[6400 + tid] = (float)dl;
    out_tail[6528 + tid] = (float)src;
    for (int t = 0; t < 50; t++) {
        int tok = captions[src * 50 + t];
        capsS[tid * 50 + t] = tok;
        out_tail[tid * 50 + t] = (float)tok;
    }
    for (int k = tid; k < 2048; k += 128) bsum[k] = bih[k] + bhh[k];
}

// ---------------- weight fp32 -> bf16 conversion ----------------
__global__ __launch_bounds__(256) void k_cvt(
    const float* __restrict__ Wih, const float* __restrict__ Whh,
    const float* __restrict__ fcW, const float* __restrict__ ihW,
    const float* __restrict__ icW,
    u16* __restrict__ WihB, u16* __restrict__ WhhB,
    u16* __restrict__ fcWB, u16* __restrict__ WhcB)
{
    int idx = blockIdx.x * 256 + threadIdx.x;  // float4 index, exact grid
    const float* src; u16* dst; int o;
    if (idx < 262144)        { src = Wih; dst = WihB; o = idx; }
    else if (idx < 524288)   { src = Whh; dst = WhhB; o = idx - 262144; }
    else if (idx < 1804288)  { src = fcW; dst = fcWB; o = idx - 524288; }
    else if (idx < 2066432)  { src = ihW; dst = WhcB; o = idx - 1804288; }
    else                     { src = icW; dst = WhcB + 1048576; o = idx - 2066432; }
    f32x4 v = *(const f32x4*)&src[(size_t)o * 4];
    us4 b = { f2bf(v.x), f2bf(v.y), f2bf(v.z), f2bf(v.w) };
    *(us4*)&dst[(size_t)o * 4] = b;
}

// ---------------- gathers: sorted enc -> bf16, embedding -> bf16 ----------------
__global__ __launch_bounds__(256) void k_gather(
    const float* __restrict__ enc, const float* __restrict__ embW,
    const int* __restrict__ sidx, const int* __restrict__ capsS,
    u16* __restrict__ encB, u16* __restrict__ Xemb)
{
    int idx = blockIdx.x * 256 + threadIdx.x;
    if (idx < 65536) {
        int b = idx >> 9, k4 = idx & 511;
        f32x4 v = *(const f32x4*)&enc[(size_t)sidx[b] * 2048 + k4 * 4];
        us4 o = { f2bf(v.x), f2bf(v.y), f2bf(v.z), f2bf(v.w) };
        *(us4*)&encB[(size_t)b * 2048 + k4 * 4] = o;
    } else {
        int j = idx - 65536;              // < 802816
        int row = j >> 7, k4 = j & 127;   // row = t*128 + b
        int t = row >> 7, b = row & 127;
        int tok = capsS[b * 50 + t];
        f32x4 v = *(const f32x4*)&embW[(size_t)tok * 512 + k4 * 4];
        us4 o = { f2bf(v.x), f2bf(v.y), f2bf(v.z), f2bf(v.w) };
        *(us4*)&Xemb[(size_t)row * 512 + k4 * 4] = o;
    }
}

// ---------------- generic 128x128 bf16 MFMA GEMM, C = A * B^T ----------------
// A: MxK bf16 row-major (lda), Bm: NxK bf16 row-major (ldb) i.e. B^T rows.
// MODE 0: X-precompute  -> outF[row*2048+col] = acc + bias[col]
// MODE 1: h0/c0         -> col<512: outH=bf16(acc+bias[col]); else outC=acc+bias2[col-512]
// MODE 2: fc            -> masked scatter into predictions
template<int MODE>
__global__ __launch_bounds__(256) void gemm128(
    const u16* __restrict__ A, int lda,
    const u16* __restrict__ Bm, int ldb, int Nreal, int K,
    const float* __restrict__ bias, const float* __restrict__ bias2,
    const int* __restrict__ dec,
    float* __restrict__ outF, u16* __restrict__ outH, float* __restrict__ outC)
{
    __shared__ u16 As[128][40];
    __shared__ u16 Bs[128][40];
    const int tid = threadIdx.x;
    const int bm = blockIdx.x, bn = blockIdx.y;
    const int w = tid >> 6, l = tid & 63;
    const int wr = (w >> 1) * 64, wc = (w & 1) * 64;
    const int lr = l & 15, lg = l >> 4;

    f32x4 acc[4][4] = {};

    for (int k0 = 0; k0 < K; k0 += 32) {
        __syncthreads();
        #pragma unroll
        for (int i = 0; i < 2; i++) {
            int L = tid * 8 + i * 2048;
            int r = L >> 5, c = L & 31;
            short8 v = *(const short8*)&A[(size_t)(bm * 128 + r) * lda + k0 + c];
            *(short8*)&As[r][c] = v;
        }
        #pragma unroll
        for (int i = 0; i < 2; i++) {
            int L = tid * 8 + i * 2048;
            int r = L >> 5, c = L & 31;
            int gn = bn * 128 + r;
            short8 v = {};
            if (gn < Nreal) v = *(const short8*)&Bm[(size_t)gn * ldb + k0 + c];
            *(short8*)&Bs[r][c] = v;
        }
        __syncthreads();
        // one MFMA per (m,n) consumes the full K=32 tile:
        // lane holds A[row=l&15][k = (l>>4)*8 + 0..7]
        short8 af[4], bfr[4];
        #pragma unroll
        for (int m = 0; m < 4; m++) af[m] = *(const short8*)&As[wr + m * 16 + lr][lg * 8];
        #pragma unroll
        for (int n = 0; n < 4; n++) bfr[n] = *(const short8*)&Bs[wc + n * 16 + lr][lg * 8];
        #pragma unroll
        for (int m = 0; m < 4; m++)
            #pragma unroll
            for (int n = 0; n < 4; n++)
                acc[m][n] = __builtin_amdgcn_mfma_f32_16x16x32_bf16(af[m], bfr[n], acc[m][n], 0, 0, 0);
    }

    #pragma unroll
    for (int m = 0; m < 4; m++) {
        #pragma unroll
        for (int n = 0; n < 4; n++) {
            #pragma unroll
            for (int i = 0; i < 4; i++) {
                int row = bm * 128 + wr + m * 16 + lg * 4 + i;
                int col = bn * 128 + wc + n * 16 + lr;
                float v = acc[m][n][i];
                if (MODE == 0) {
                    outF[(size_t)row * 2048 + col] = v + bias[col];
                } else if (MODE == 1) {
                    if (col < 512) outH[row * 512 + col] = f2bf(v + bias[col]);
                    else outC[row * 512 + (col - 512)] = v + bias2[col - 512];
                } else {
                    if (col < Nreal) {
                        int b = row & 127, t = row >> 7;
                        float o = (t < dec[b]) ? (v + bias[col]) : 0.0f;
                        outF[(size_t)b * ((size_t)TM * NV) + (size_t)t * NV + col] = o;
                    }
                }
            }
        }
    }
}

// ---------------- one LSTM time step (gates MFMA + fused pointwise) ----------------
// grid 64 = 4 row-blocks x 16 col-blocks of the 128x512 h/c state.
// wave g computes gate g's 32x32 tile: gates = X[t] + h @ Whh^T
__global__ __launch_bounds__(256) void lstm_step(
    const u16* __restrict__ hin, u16* __restrict__ hout,
    float* __restrict__ c, const u16* __restrict__ Whh,
    const float* __restrict__ Xt, u16* __restrict__ HnewT,
    const int* __restrict__ dec, int t)
{
    __shared__ u16 As[32][520];       // h rows, full K=512, padded
    __shared__ u16 Bs[128][40];       // 4 gates x 32 cols, BK=32
    __shared__ float gs[4][32][40];   // gate exchange
    const int tid = threadIdx.x;
    const int rb = blockIdx.x >> 4, cb = blockIdx.x & 15;
    const int g = tid >> 6, l = tid & 63;
    const int lr = l & 15, lg = l >> 4;

    #pragma unroll
    for (int i = 0; i < 8; i++) {
        int L = tid * 8 + i * 2048;
        int r = L >> 9, cc = L & 511;
        *(short8*)&As[r][cc] = *(const short8*)&hin[(size_t)(rb * 32 + r) * 512 + cc];
    }

    f32x4 acc[2][2] = {};
    for (int k0 = 0; k0 < 512; k0 += 32) {
        __syncthreads();
        #pragma unroll
        for (int i = 0; i < 2; i++) {
            int L = tid * 8 + i * 2048;
            int r = L >> 5, cc = L & 31;
            int gate = r >> 5, nn = r & 31;
            *(short8*)&Bs[r][cc] =
                *(const short8*)&Whh[(size_t)(gate * 512 + cb * 32 + nn) * 512 + k0 + cc];
        }
        __syncthreads();
        short8 af[2], bfr[2];
        #pragma unroll
        for (int m = 0; m < 2; m++) af[m] = *(const short8*)&As[m * 16 + lr][k0 + lg * 8];
        #pragma unroll
        for (int n = 0; n < 2; n++) bfr[n] = *(const short8*)&Bs[g * 32 + n * 16 + lr][lg * 8];
        #pragma unroll
        for (int m = 0; m < 2; m++)
            #pragma unroll
            for (int n = 0; n < 2; n++)
                acc[m][n] = __builtin_amdgcn_mfma_f32_16x16x32_bf16(af[m], bfr[n], acc[m][n], 0, 0, 0);
    }

    #pragma unroll
    for (int m = 0; m < 2; m++)
        #pragma unroll
        for (int n = 0; n < 2; n++)
            #pragma unroll
            for (int i = 0; i < 4; i++)
                gs[g][m * 16 + lg * 4 + i][n * 16 + lr] = acc[m][n][i];
    __syncthreads();

    {
        int row = tid >> 3;            // 0..31
        int c4  = (tid & 7) * 4;       // 0..28
        int gr = rb * 32 + row;        // batch row (sorted order)
        int gc = cb * 32 + c4;         // hidden col
        f32x4 gi = *(const f32x4*)&gs[0][row][c4];
        f32x4 gf = *(const f32x4*)&gs[1][row][c4];
        f32x4 gg = *(const f32x4*)&gs[2][row][c4];
        f32x4 go = *(const f32x4*)&gs[3][row][c4];
        size_t xb = (size_t)gr * 2048 + gc;
        f32x4 xi = *(const f32x4*)&Xt[xb];
        f32x4 xf = *(const f32x4*)&Xt[xb + 512];
        f32x4 xg = *(const f32x4*)&Xt[xb + 1024];
        f32x4 xo = *(const f32x4*)&Xt[xb + 1536];
        f32x4 cold = *(const f32x4*)&c[(size_t)gr * 512 + gc];
        int act = (t < dec[gr]);
        f32x4 cnew4; us4 hv, hn;
        #pragma unroll
        for (int j = 0; j < 4; j++) {
            float iv = sigm(gi[j] + xi[j]);
            float fv = sigm(gf[j] + xf[j]);
            float gv = tanhf(gg[j] + xg[j]);
            float ov = sigm(go[j] + xo[j]);
            float cn = fv * cold[j] + iv * gv;
            float hn_f = ov * tanhf(cn);
            cnew4[j] = act ? cn : cold[j];
            float hold = bf2f(As[row][gc + j]);
            float ho = act ? hn_f : hold;
            hv[j] = f2bf(ho);
            hn[j] = f2bf(hn_f);
        }
        *(f32x4*)&c[(size_t)gr * 512 + gc] = cnew4;
        *(us4*)&hout[(size_t)gr * 512 + gc] = hv;
        *(us4*)&HnewT[(size_t)gr * 512 + gc] = hn;
    }
}

extern "C" void kernel_launch(void* const* d_in, const int* in_sizes, int n_in,
                              void* d_out, int out_size, void* d_ws, size_t ws_size,
                              hipStream_t stream) {
    const float* enc      = (const float*)d_in[0];
    const int*   captions = (const int*)d_in[1];
    const int*   caplens  = (const int*)d_in[2];
    const float* embW     = (const float*)d_in[3];
    const float* Wih      = (const float*)d_in[4];
    const float* Whh      = (const float*)d_in[5];
    const float* bih      = (const float*)d_in[6];
    const float* bhh      = (const float*)d_in[7];
    const float* fcW      = (const float*)d_in[8];
    const float* fcb      = (const float*)d_in[9];
    const float* ihW      = (const float*)d_in[10];
    const float* ihb      = (const float*)d_in[11];
    const float* icW      = (const float*)d_in[12];
    const float* icb      = (const float*)d_in[13];
    float* out = (float*)d_out;

    char* ws = (char*)d_ws;
    u16*   WihB = (u16*)(ws + 0);
    u16*   WhhB = (u16*)(ws + 2097152);
    u16*   fcWB = (u16*)(ws + 4194304);
    u16*   WhcB = (u16*)(ws + 14434304);
    u16*   encB = (u16*)(ws + 18628608);
    u16*   Xemb = (u16*)(ws + 19152896);
    float* X    = (float*)(ws + 25575424);
    u16*   Hnew = (u16*)(ws + 76955648);
    u16*   hb0  = (u16*)(ws + 83378176);
    u16*   hb1  = (u16*)(ws + 83509248);
    float* cf   = (float*)(ws + 83640320);
    int*   sidx = (int*)(ws + 83902464);
    int*   decl = (int*)(ws + 83902976);
    int*   capsS= (int*)(ws + 83903488);
    float* bsum = (float*)(ws + 83929088);

    k_sort<<<1, 128, 0, stream>>>(caplens, captions, bih, bhh, sidx, decl, capsS, bsum,
                                  out + 62720000);
    k_cvt<<<9096, 256, 0, stream>>>(Wih, Whh, fcW, ihW, icW, WihB, WhhB, fcWB, WhcB);
    k_gather<<<3392, 256, 0, stream>>>(enc, embW, sidx, capsS, encB, Xemb);
    // h0 | c0 : (128 x 1024) = encB (128x2048) @ WhcB^T
    gemm128<1><<<dim3(1, 8), 256, 0, stream>>>(encB, 2048, WhcB, 2048, 1024, 2048,
                                               ihb, icb, nullptr, nullptr, hb0, cf);
    // X = Xemb (6272x512) @ WihB^T (2048x512) + (b_ih+b_hh)
    gemm128<0><<<dim3(49, 16), 256, 0, stream>>>(Xemb, 512, WihB, 512, 2048, 512,
                                                 bsum, nullptr, nullptr, X, nullptr, nullptr);
    for (int t = 0; t < TM; t++) {
        const u16* hin = (t & 1) ? hb1 : hb0;
        u16* hout = (t & 1) ? hb0 : hb1;
        lstm_step<<<64, 256, 0, stream>>>(hin, hout, cf, WhhB,
                                          X + (size_t)t * 128 * 2048,
                                          Hnew + (size_t)t * 128 * 512, decl, t);
    }
    // predictions = Hnew (6272x512) @ fcWB^T (10000x512) + fc_b, masked
    gemm128<2><<<dim3(49, 79), 256, 0, stream>>>(Hnew, 512, fcWB, 512, NV, 512,
                                                 fcb, nullptr, decl, out, nullptr, nullptr);
}